// Round 2
// baseline (369.325 us; speedup 1.0000x reference)
//
#include <hip/hip_runtime.h>
#include <math.h>

typedef int   v2i __attribute__((ext_vector_type(2)));
typedef int   v4i __attribute__((ext_vector_type(4)));
typedef float v2f __attribute__((ext_vector_type(2)));
typedef float v4f __attribute__((ext_vector_type(4)));

// ---- marching-tets tables ----
__constant__ int c_tri_table[16][6] = {
    {-1,-1,-1,-1,-1,-1},{1,0,2,-1,-1,-1},{4,0,3,-1,-1,-1},{1,4,2,1,3,4},
    {3,1,5,-1,-1,-1},{2,3,0,2,5,3},{1,4,0,1,5,4},{4,2,5,-1,-1,-1},
    {4,5,2,-1,-1,-1},{4,1,0,4,5,1},{3,2,0,3,5,2},{1,3,5,-1,-1,-1},
    {4,1,2,4,3,1},{3,0,4,-1,-1,-1},{2,0,1,-1,-1,-1},{-1,-1,-1,-1,-1,-1}};
__constant__ int c_num_tri[16] = {0,1,1,2,1,2,2,1,1,2,2,1,2,1,1,0};

// Per-unique-edge vertex interpolation. 2 edges per thread.
// Streams (edges in, verts out) are non-temporal so L2 keeps pos/sdf.
__global__ void __launch_bounds__(256) dmtet_verts_kernel(
        const float* __restrict__ pos,
        const float* __restrict__ sdf,
        const int* __restrict__ edges,
        float* __restrict__ verts, int Eu) {
    int t = blockIdx.x * blockDim.x + threadIdx.x;
    int e0 = 2 * t;
    if (e0 >= Eu) return;

    int ax, ay, bx, by;
    bool have2 = (e0 + 1 < Eu);
    if (have2) {
        v4i ed = __builtin_nontemporal_load((const v4i*)(edges + 2 * e0));
        ax = ed.x; ay = ed.y; bx = ed.z; by = ed.w;
    } else {
        v2i ed = __builtin_nontemporal_load((const v2i*)(edges + 2 * e0));
        ax = ed.x; ay = ed.y; bx = ed.x; by = ed.y;
    }

    // issue all gathers up front (MLP)
    float sa0 = sdf[ax], sa1 = sdf[ay];
    float sb0 = sdf[bx], sb1 = sdf[by];
    const float* pa0 = pos + 3LL * ax;
    const float* pa1 = pos + 3LL * ay;
    const float* pb0 = pos + 3LL * bx;
    const float* pb1 = pos + 3LL * by;
    float a0x = pa0[0], a0y = pa0[1], a0z = pa0[2];
    float a1x = pa1[0], a1y = pa1[1], a1z = pa1[2];
    float b0x = pb0[0], b0y = pb0[1], b0z = pb0[2];
    float b1x = pb1[0], b1y = pb1[1], b1z = pb1[2];

    bool ca = (sa0 > 0.0f) != (sa1 > 0.0f);
    float da = ca ? (sa0 - sa1) : 1.0f;
    float ia = 1.0f / da;
    float wa0 = -sa1 * ia, wa1 = sa0 * ia;
    float ox0 = ca ? (a0x * wa0 + a1x * wa1) : 0.0f;
    float oy0 = ca ? (a0y * wa0 + a1y * wa1) : 0.0f;
    float oz0 = ca ? (a0z * wa0 + a1z * wa1) : 0.0f;

    bool cb = (sb0 > 0.0f) != (sb1 > 0.0f);
    float db = cb ? (sb0 - sb1) : 1.0f;
    float ib = 1.0f / db;
    float wb0 = -sb1 * ib, wb1 = sb0 * ib;
    float ox1 = cb ? (b0x * wb0 + b1x * wb1) : 0.0f;
    float oy1 = cb ? (b0y * wb0 + b1y * wb1) : 0.0f;
    float oz1 = cb ? (b0z * wb0 + b1z * wb1) : 0.0f;

    float* o = verts + 3LL * e0;
    __builtin_nontemporal_store(ox0, o + 0);
    __builtin_nontemporal_store(oy0, o + 1);
    __builtin_nontemporal_store(oz0, o + 2);
    if (have2) {
        __builtin_nontemporal_store(ox1, o + 3);
        __builtin_nontemporal_store(oy1, o + 4);
        __builtin_nontemporal_store(oz1, o + 5);
    }
}

// Per-tet: faces (T,2,3) and uv_idx (T,2,3), both written as float32.
__global__ void __launch_bounds__(256) dmtet_tets_kernel(
        const float* __restrict__ sdf,
        const int* __restrict__ tets,
        const int* __restrict__ idx_map,
        float* __restrict__ faces_out,
        float* __restrict__ uvidx_out, int T) {
    int t = blockIdx.x * blockDim.x + threadIdx.x;
    if (t >= T) return;

    v4i v = __builtin_nontemporal_load((const v4i*)(tets + 4LL * t));
    v4i m0 = __builtin_nontemporal_load((const v4i*)(idx_map + 6LL * t));
    v2i m1 = __builtin_nontemporal_load((const v2i*)(idx_map + 6LL * t + 4));

    int idx = (sdf[v.x] > 0.0f ? 1 : 0) | (sdf[v.y] > 0.0f ? 2 : 0) |
              (sdf[v.z] > 0.0f ? 4 : 0) | (sdf[v.w] > 0.0f ? 8 : 0);
    int  ntri  = c_num_tri[idx];
    bool valid = (idx != 0) && (idx != 15);

    int im[6] = {m0.x, m0.y, m0.z, m0.w, m1.x, m1.y};

    long long o = 6LL * t;
    #pragma unroll
    for (int j = 0; j < 6; ++j) {
        bool tv = valid && ((j < 3) ? (ntri > 0) : (ntri > 1));
        int tri = c_tri_table[idx][j];
        int cl = tri < 0 ? 0 : tri;          // clip(tri, 0, 5)
        __builtin_nontemporal_store((float)(tv ? im[cl] : -1), faces_out + o + j);
    }

    int base = 4 * t;   // tet_idx == t since T == Ngrid*Ngrid here
    bool tv0 = valid && (ntri > 0);
    bool tv1 = valid && (ntri > 1);
    __builtin_nontemporal_store(tv0 ? (float)(base)     : -1.0f, uvidx_out + o + 0);
    __builtin_nontemporal_store(tv0 ? (float)(base + 1) : -1.0f, uvidx_out + o + 1);
    __builtin_nontemporal_store(tv0 ? (float)(base + 2) : -1.0f, uvidx_out + o + 2);
    __builtin_nontemporal_store(tv1 ? (float)(base)     : -1.0f, uvidx_out + o + 3);
    __builtin_nontemporal_store(tv1 ? (float)(base + 2) : -1.0f, uvidx_out + o + 4);
    __builtin_nontemporal_store(tv1 ? (float)(base + 3) : -1.0f, uvidx_out + o + 5);
}

// UV atlas fill: each thread writes one float4 = two (u,v) corners.
__global__ void __launch_bounds__(256) dmtet_uvs_kernel(
        v4f* __restrict__ uvs, int Ngrid, int npairs, float step, float pad) {
    int k = blockIdx.x * blockDim.x + threadIdx.x;   // pair id
    if (k >= npairs) return;
    int q = k >> 1;      // quad id
    int h = k & 1;       // 0: corners {0,1}, 1: corners {2,3}
    int gx = q % Ngrid;
    int gy = q / Ngrid;
    float x = (float)gx * step;
    float y = (float)gy * step;
    v4f out;
    if (h == 0) { out.x = x;       out.y = y;       out.z = x + pad; out.w = y; }
    else        { out.x = x + pad; out.y = y + pad; out.z = x;       out.w = y + pad; }
    __builtin_nontemporal_store(out, uvs + k);
}

extern "C" void kernel_launch(void* const* d_in, const int* in_sizes, int n_in,
                              void* d_out, int out_size, void* d_ws, size_t ws_size,
                              hipStream_t stream) {
    const float* pos     = (const float*)d_in[0];
    const float* sdf     = (const float*)d_in[1];
    const int*   tet     = (const int*)d_in[2];
    const int*   edges   = (const int*)d_in[3];
    const int*   idx_map = (const int*)d_in[4];

    int T  = in_sizes[2] / 4;
    int Eu = in_sizes[3] / 2;

    long long half = (2LL * T + 1) / 2;
    int Ngrid = (int)ceil(sqrt((double)half));
    while ((long long)Ngrid * Ngrid < half) Ngrid++;            // safety
    while ((long long)(Ngrid - 1) * (Ngrid - 1) >= half) Ngrid--;

    float* out   = (float*)d_out;
    float* verts = out;
    float* faces = verts + 3LL * Eu;
    float* uvs   = faces + 6LL * T;
    float* uvidx = uvs   + 8LL * Ngrid * Ngrid;

    float step = (float)((1.0 - 1.0 / (double)Ngrid) / (double)(Ngrid - 1));
    float pad  = 0.9f / (float)Ngrid;

    const int BLK = 256;

    int vthreads = (Eu + 1) / 2;
    dmtet_verts_kernel<<<(vthreads + BLK - 1) / BLK, BLK, 0, stream>>>(
        pos, sdf, edges, verts, Eu);

    dmtet_tets_kernel<<<(T + BLK - 1) / BLK, BLK, 0, stream>>>(
        sdf, tet, idx_map, faces, uvidx, T);

    int npairs = Ngrid * Ngrid * 2;
    dmtet_uvs_kernel<<<(npairs + BLK - 1) / BLK, BLK, 0, stream>>>(
        (v4f*)uvs, Ngrid, npairs, step, pad);
}

// Round 4
// 301.347 us; speedup vs baseline: 1.2256x; 1.2256x over previous
//
#include <hip/hip_runtime.h>
#include <math.h>

typedef int   v2i __attribute__((ext_vector_type(2)));
typedef int   v4i __attribute__((ext_vector_type(4)));
typedef float v2f __attribute__((ext_vector_type(2)));
typedef float v4f __attribute__((ext_vector_type(4)));

// Packed marching-tets rows: entry j = (tri_table[idx][j]+1) << (3*j)  (3 bits,
// 0 means "-1 / unused"), plus num_tri << 18. Generated from TRI_TABLE.
__constant__ int c_tri_pack[16] = {
    0,      262346, 262413, 705770, 262548, 681571, 713834, 262557,
    262389, 617045, 649308, 262562, 608981, 262476, 262283, 0};

// ---- pack {pos.xyz, sdf} into float4 per vertex (into d_ws) ----
__global__ void __launch_bounds__(256) pack_kernel(
        const float* __restrict__ pos, const float* __restrict__ sdf,
        v4f* __restrict__ packed, int N) {
    int t = blockIdx.x * blockDim.x + threadIdx.x;
    int v0 = 4 * t;
    if (v0 + 4 <= N) {
        const v4f* pos4 = (const v4f*)pos;
        v4f p0 = pos4[3LL * t], p1 = pos4[3LL * t + 1], p2 = pos4[3LL * t + 2];
        v4f s  = ((const v4f*)sdf)[t];
        v4f o0 = {p0.x, p0.y, p0.z, s.x};
        v4f o1 = {p0.w, p1.x, p1.y, s.y};
        v4f o2 = {p1.z, p1.w, p2.x, s.z};
        v4f o3 = {p2.y, p2.z, p2.w, s.w};
        packed[v0 + 0] = o0; packed[v0 + 1] = o1;
        packed[v0 + 2] = o2; packed[v0 + 3] = o3;
    } else {
        for (int v = v0; v < N; ++v) {
            v4f o = {pos[3LL * v], pos[3LL * v + 1], pos[3LL * v + 2], sdf[v]};
            packed[v] = o;
        }
    }
}

// ---- fused: [verts blocks | tets blocks | uvs blocks] ----
__global__ void __launch_bounds__(256) dmtet_fused_kernel(
        const float* __restrict__ pos,
        const float* __restrict__ sdf,
        const int* __restrict__ tet,
        const int* __restrict__ edges,
        const int* __restrict__ idx_map,
        const v4f* __restrict__ packed,        // may be null (fallback)
        float* __restrict__ verts,
        float* __restrict__ faces_out,
        float* __restrict__ uvidx_out,
        v4f* __restrict__ uvs,
        int Eu, int T, int Ngrid,
        int vBlocks, int tBlocks,
        float step, float pad) {
    int b = blockIdx.x;

    if (b < vBlocks) {
        // ---------- vertex interpolation: 2 edges per thread ----------
        int t = b * blockDim.x + threadIdx.x;
        int e0 = 2 * t;
        if (e0 >= Eu) return;
        bool have2 = (e0 + 1 < Eu);

        int ax, ay, bx, by;
        if (have2) {
            v4i ed = __builtin_nontemporal_load((const v4i*)(edges + 4LL * t));
            ax = ed.x; ay = ed.y; bx = ed.z; by = ed.w;
        } else {
            v2i ed = __builtin_nontemporal_load((const v2i*)(edges + 2LL * e0));
            ax = ed.x; ay = ed.y; bx = ed.x; by = ed.y;
        }

        float a0x, a0y, a0z, sa0, a1x, a1y, a1z, sa1;
        float b0x, b0y, b0z, sb0, b1x, b1y, b1z, sb1;
        if (packed) {
            v4f A0 = packed[ax], A1 = packed[ay];
            v4f B0 = packed[bx], B1 = packed[by];
            a0x = A0.x; a0y = A0.y; a0z = A0.z; sa0 = A0.w;
            a1x = A1.x; a1y = A1.y; a1z = A1.z; sa1 = A1.w;
            b0x = B0.x; b0y = B0.y; b0z = B0.z; sb0 = B0.w;
            b1x = B1.x; b1y = B1.y; b1z = B1.z; sb1 = B1.w;
        } else {
            sa0 = sdf[ax]; sa1 = sdf[ay]; sb0 = sdf[bx]; sb1 = sdf[by];
            const float* pa0 = pos + 3LL * ax;
            const float* pa1 = pos + 3LL * ay;
            const float* pb0 = pos + 3LL * bx;
            const float* pb1 = pos + 3LL * by;
            a0x = pa0[0]; a0y = pa0[1]; a0z = pa0[2];
            a1x = pa1[0]; a1y = pa1[1]; a1z = pa1[2];
            b0x = pb0[0]; b0y = pb0[1]; b0z = pb0[2];
            b1x = pb1[0]; b1y = pb1[1]; b1z = pb1[2];
        }

        bool ca = (sa0 > 0.0f) != (sa1 > 0.0f);
        float da = ca ? (sa0 - sa1) : 1.0f;
        float wa0 = -sa1 / da, wa1 = sa0 / da;
        float ox0 = ca ? (a0x * wa0 + a1x * wa1) : 0.0f;
        float oy0 = ca ? (a0y * wa0 + a1y * wa1) : 0.0f;
        float oz0 = ca ? (a0z * wa0 + a1z * wa1) : 0.0f;

        bool cb = (sb0 > 0.0f) != (sb1 > 0.0f);
        float db = cb ? (sb0 - sb1) : 1.0f;
        float wb0 = -sb1 / db, wb1 = sb0 / db;
        float ox1 = cb ? (b0x * wb0 + b1x * wb1) : 0.0f;
        float oy1 = cb ? (b0y * wb0 + b1y * wb1) : 0.0f;
        float oz1 = cb ? (b0z * wb0 + b1z * wb1) : 0.0f;

        float* o = verts + 3LL * e0;
        if (have2) {
            v2f s0 = {ox0, oy0}, s1 = {oz0, ox1}, s2 = {oy1, oz1};
            ((v2f*)o)[0] = s0; ((v2f*)o)[1] = s1; ((v2f*)o)[2] = s2;
        } else {
            o[0] = ox0; o[1] = oy0; o[2] = oz0;
        }
    } else if (b < vBlocks + tBlocks) {
        // ---------- per-tet faces + uv_idx ----------
        int t = (b - vBlocks) * blockDim.x + threadIdx.x;
        if (t >= T) return;

        v4i v  = __builtin_nontemporal_load((const v4i*)(tet + 4LL * t));
        v4i m0 = __builtin_nontemporal_load((const v4i*)(idx_map + 6LL * t));
        v2i m1 = __builtin_nontemporal_load((const v2i*)(idx_map + 6LL * t + 4));

        int idx = (sdf[v.x] > 0.0f ? 1 : 0) | (sdf[v.y] > 0.0f ? 2 : 0) |
                  (sdf[v.z] > 0.0f ? 4 : 0) | (sdf[v.w] > 0.0f ? 8 : 0);
        int row = c_tri_pack[idx];

        float f[6];
        #pragma unroll
        for (int j = 0; j < 6; ++j) {
            int tri3 = (row >> (3 * j)) & 7;        // tri+1, 0 = unused
            int cl = tri3 - 1;                       // valid only when tri3>0
            int pick = m0.x;
            pick = (cl == 1) ? m0.y : pick;
            pick = (cl == 2) ? m0.z : pick;
            pick = (cl == 3) ? m0.w : pick;
            pick = (cl == 4) ? m1.x : pick;
            pick = (cl == 5) ? m1.y : pick;
            f[j] = (tri3 != 0) ? (float)pick : -1.0f;
        }
        long long o = 6LL * t;
        {
            v2f s0 = {f[0], f[1]}, s1 = {f[2], f[3]}, s2 = {f[4], f[5]};
            v2f* fo = (v2f*)(faces_out + o);
            fo[0] = s0; fo[1] = s1; fo[2] = s2;
        }

        int base = 4 * t;   // tet_idx == t since T == Ngrid*Ngrid
        bool tv0 = (row & 7) != 0;          // ntri > 0 (and tet valid)
        bool tv1 = ((row >> 9) & 7) != 0;   // ntri > 1
        float u0 = tv0 ? (float)(base)     : -1.0f;
        float u1 = tv0 ? (float)(base + 1) : -1.0f;
        float u2 = tv0 ? (float)(base + 2) : -1.0f;
        float u3 = tv1 ? (float)(base)     : -1.0f;
        float u4 = tv1 ? (float)(base + 2) : -1.0f;
        float u5 = tv1 ? (float)(base + 3) : -1.0f;
        v2f s0 = {u0, u1}, s1 = {u2, u3}, s2 = {u4, u5};
        v2f* uo = (v2f*)(uvidx_out + o);
        uo[0] = s0; uo[1] = s1; uo[2] = s2;
    } else {
        // ---------- UV atlas: one float4 (two corners) per thread ----------
        int k = (b - vBlocks - tBlocks) * blockDim.x + threadIdx.x;
        int npairs = Ngrid * Ngrid * 2;
        if (k >= npairs) return;
        int q = k >> 1;
        int h = k & 1;
        int gx = q % Ngrid;
        int gy = q / Ngrid;
        float x = (float)gx * step;
        float y = (float)gy * step;
        v4f out;
        if (h == 0) { out.x = x;       out.y = y;       out.z = x + pad; out.w = y; }
        else        { out.x = x + pad; out.y = y + pad; out.z = x;       out.w = y + pad; }
        uvs[k] = out;
    }
}

extern "C" void kernel_launch(void* const* d_in, const int* in_sizes, int n_in,
                              void* d_out, int out_size, void* d_ws, size_t ws_size,
                              hipStream_t stream) {
    const float* pos     = (const float*)d_in[0];
    const float* sdf     = (const float*)d_in[1];
    const int*   tet     = (const int*)d_in[2];
    const int*   edges   = (const int*)d_in[3];
    const int*   idx_map = (const int*)d_in[4];

    int Nv = in_sizes[0] / 3;
    int T  = in_sizes[2] / 4;
    int Eu = in_sizes[3] / 2;

    long long half = (2LL * T + 1) / 2;
    int Ngrid = (int)ceil(sqrt((double)half));
    while ((long long)Ngrid * Ngrid < half) Ngrid++;
    while ((long long)(Ngrid - 1) * (Ngrid - 1) >= half) Ngrid--;

    float* out   = (float*)d_out;
    float* verts = out;
    float* faces = verts + 3LL * Eu;
    float* uvs   = faces + 6LL * T;
    float* uvidx = uvs   + 8LL * Ngrid * Ngrid;

    float step = (float)((1.0 - 1.0 / (double)Ngrid) / (double)(Ngrid - 1));
    float pad  = 0.9f / (float)Ngrid;

    const int BLK = 256;
    bool usePacked = (ws_size >= (size_t)Nv * 16);
    v4f* packed = usePacked ? (v4f*)d_ws : nullptr;

    if (usePacked) {
        int pthreads = (Nv + 3) / 4;
        pack_kernel<<<(pthreads + BLK - 1) / BLK, BLK, 0, stream>>>(
            pos, sdf, packed, Nv);
    }

    int vthreads = (Eu + 1) / 2;
    int vBlocks = (vthreads + BLK - 1) / BLK;
    int tBlocks = (T + BLK - 1) / BLK;
    int npairs  = Ngrid * Ngrid * 2;
    int uBlocks = (npairs + BLK - 1) / BLK;

    dmtet_fused_kernel<<<vBlocks + tBlocks + uBlocks, BLK, 0, stream>>>(
        pos, sdf, tet, edges, idx_map, packed,
        verts, faces, uvidx, (v4f*)uvs,
        Eu, T, Ngrid, vBlocks, tBlocks, step, pad);
}

// Round 7
// 292.787 us; speedup vs baseline: 1.2614x; 1.0292x over previous
//
#include <hip/hip_runtime.h>
#include <math.h>

typedef int      v2i __attribute__((ext_vector_type(2)));
typedef int      v4i __attribute__((ext_vector_type(4)));
typedef float    v2f __attribute__((ext_vector_type(2)));
typedef float    v4f __attribute__((ext_vector_type(4)));
typedef _Float16 v4h __attribute__((ext_vector_type(4)));

// Packed marching-tets rows: entry j = (tri_table[idx][j]+1) << (3*j)  (3 bits,
// 0 means "-1 / unused"), plus num_tri << 18. Generated from TRI_TABLE.
__constant__ int c_tri_pack[16] = {
    0,      262346, 262413, 705770, 262548, 681571, 713834, 262557,
    262389, 617045, 649308, 262562, 608981, 262476, 262283, 0};

// ---- pack {pos.xyz, sdf} into half4 (8 B) per vertex (into d_ws) ----
// Gather working set: 600K * 8B = 4.8 MB -> ~L2-resident per XCD.
__global__ void __launch_bounds__(256) pack_kernel(
        const float* __restrict__ pos, const float* __restrict__ sdf,
        v4h* __restrict__ packed, int N) {
    int t = blockIdx.x * blockDim.x + threadIdx.x;
    int v0 = 4 * t;
    if (v0 >= N) return;

    // fp16 sign-preserving sdf: tiny positive must stay positive so the
    // crossing mask matches the f32 sign test used in the tets phase.
    auto h_sdf = [](float s) -> _Float16 {
        _Float16 h = (_Float16)s;
        if (s > 0.0f && !(h > (_Float16)0)) h = (_Float16)6.0e-8f;
        return h;
    };

    if (v0 + 4 <= N) {
        const v4f* pos4 = (const v4f*)pos;
        v4f p0 = pos4[3LL * t], p1 = pos4[3LL * t + 1], p2 = pos4[3LL * t + 2];
        v4f s  = ((const v4f*)sdf)[t];
        v4h h0 = {(_Float16)p0.x, (_Float16)p0.y, (_Float16)p0.z, h_sdf(s.x)};
        v4h h1 = {(_Float16)p0.w, (_Float16)p1.x, (_Float16)p1.y, h_sdf(s.y)};
        v4h h2 = {(_Float16)p1.z, (_Float16)p1.w, (_Float16)p2.x, h_sdf(s.z)};
        v4h h3 = {(_Float16)p2.y, (_Float16)p2.z, (_Float16)p2.w, h_sdf(s.w)};
        // combine pairs into 16B stores
        v4f o01, o23;
        ((v4h*)&o01)[0] = h0; ((v4h*)&o01)[1] = h1;
        ((v4h*)&o23)[0] = h2; ((v4h*)&o23)[1] = h3;
        v4f* dst = (v4f*)(packed + v0);
        dst[0] = o01; dst[1] = o23;
    } else {
        for (int v = v0; v < N; ++v) {
            v4h o = {(_Float16)pos[3LL * v], (_Float16)pos[3LL * v + 1],
                     (_Float16)pos[3LL * v + 2], h_sdf(sdf[v])};
            packed[v] = o;
        }
    }
}

__device__ __forceinline__ void interp_edge(v4h P0, v4h P1,
                                            float& ox, float& oy, float& oz) {
    float s0 = (float)P0.w, s1 = (float)P1.w;
    bool c = (s0 > 0.0f) != (s1 > 0.0f);
    float d = c ? (s0 - s1) : 1.0f;
    float w0 = -s1 / d, w1 = s0 / d;
    ox = c ? ((float)P0.x * w0 + (float)P1.x * w1) : 0.0f;
    oy = c ? ((float)P0.y * w0 + (float)P1.y * w1) : 0.0f;
    oz = c ? ((float)P0.z * w0 + (float)P1.z * w1) : 0.0f;
}

// ---- fused: [verts blocks | tets blocks | uvs blocks] ----
__global__ void __launch_bounds__(256) dmtet_fused_kernel(
        const float* __restrict__ pos,
        const float* __restrict__ sdf,
        const int* __restrict__ tet,
        const int* __restrict__ edges,
        const int* __restrict__ idx_map,
        const v4h* __restrict__ packed,        // may be null (fallback)
        float* __restrict__ verts,
        float* __restrict__ faces_out,
        float* __restrict__ uvidx_out,
        v4f* __restrict__ uvs,
        int Eu, int T, int Ngrid,
        int vBlocks, int tBlocks,
        float step, float pad) {
    int b = blockIdx.x;

    if (b < vBlocks) {
        // ---------- vertex interpolation: 4 edges per thread ----------
        int t = b * blockDim.x + threadIdx.x;
        int e0 = 4 * t;
        if (e0 >= Eu) return;

        if (packed && e0 + 4 <= Eu) {
            v4i edA = __builtin_nontemporal_load((const v4i*)(edges + 2LL * e0));
            v4i edB = __builtin_nontemporal_load((const v4i*)(edges + 2LL * e0 + 4));
            // issue all 8 gathers up front (MLP)
            v4h P0 = packed[edA.x], P1 = packed[edA.y];
            v4h P2 = packed[edA.z], P3 = packed[edA.w];
            v4h P4 = packed[edB.x], P5 = packed[edB.y];
            v4h P6 = packed[edB.z], P7 = packed[edB.w];

            float x0,y0,z0,x1,y1,z1,x2,y2,z2,x3,y3,z3;
            interp_edge(P0, P1, x0, y0, z0);
            interp_edge(P2, P3, x1, y1, z1);
            interp_edge(P4, P5, x2, y2, z2);
            interp_edge(P6, P7, x3, y3, z3);

            v4f r0 = {x0, y0, z0, x1};
            v4f r1 = {y1, z1, x2, y2};
            v4f r2 = {z2, x3, y3, z3};
            v4f* o = (v4f*)(verts + 3LL * e0);
            o[0] = r0; o[1] = r1; o[2] = r2;
        } else {
            int eEnd = (e0 + 4 < Eu) ? e0 + 4 : Eu;
            for (int e = e0; e < eEnd; ++e) {
                v2i ed = *(const v2i*)(edges + 2LL * e);
                float ox, oy, oz;
                if (packed) {
                    interp_edge(packed[ed.x], packed[ed.y], ox, oy, oz);
                } else {
                    float s0 = sdf[ed.x], s1 = sdf[ed.y];
                    bool c = (s0 > 0.0f) != (s1 > 0.0f);
                    float d = c ? (s0 - s1) : 1.0f;
                    float w0 = -s1 / d, w1 = s0 / d;
                    const float* p0 = pos + 3LL * ed.x;
                    const float* p1 = pos + 3LL * ed.y;
                    ox = c ? (p0[0] * w0 + p1[0] * w1) : 0.0f;
                    oy = c ? (p0[1] * w0 + p1[1] * w1) : 0.0f;
                    oz = c ? (p0[2] * w0 + p1[2] * w1) : 0.0f;
                }
                verts[3LL * e + 0] = ox;
                verts[3LL * e + 1] = oy;
                verts[3LL * e + 2] = oz;
            }
        }
    } else if (b < vBlocks + tBlocks) {
        // ---------- per-tet faces + uv_idx ----------
        int t = (b - vBlocks) * blockDim.x + threadIdx.x;
        if (t >= T) return;

        v4i v  = __builtin_nontemporal_load((const v4i*)(tet + 4LL * t));
        v4i m0 = __builtin_nontemporal_load((const v4i*)(idx_map + 6LL * t));
        v2i m1 = __builtin_nontemporal_load((const v2i*)(idx_map + 6LL * t + 4));

        int idx = (sdf[v.x] > 0.0f ? 1 : 0) | (sdf[v.y] > 0.0f ? 2 : 0) |
                  (sdf[v.z] > 0.0f ? 4 : 0) | (sdf[v.w] > 0.0f ? 8 : 0);
        int row = c_tri_pack[idx];

        float f[6];
        #pragma unroll
        for (int j = 0; j < 6; ++j) {
            int tri3 = (row >> (3 * j)) & 7;        // tri+1, 0 = unused
            int cl = tri3 - 1;                       // valid only when tri3>0
            int pick = m0.x;
            pick = (cl == 1) ? m0.y : pick;
            pick = (cl == 2) ? m0.z : pick;
            pick = (cl == 3) ? m0.w : pick;
            pick = (cl == 4) ? m1.x : pick;
            pick = (cl == 5) ? m1.y : pick;
            f[j] = (tri3 != 0) ? (float)pick : -1.0f;
        }
        long long o = 6LL * t;
        {
            v2f s0 = {f[0], f[1]}, s1 = {f[2], f[3]}, s2 = {f[4], f[5]};
            v2f* fo = (v2f*)(faces_out + o);
            fo[0] = s0; fo[1] = s1; fo[2] = s2;
        }

        int base = 4 * t;   // tet_idx == t since T == Ngrid*Ngrid
        bool tv0 = (row & 7) != 0;          // ntri > 0 (and tet valid)
        bool tv1 = ((row >> 9) & 7) != 0;   // ntri > 1
        float u0 = tv0 ? (float)(base)     : -1.0f;
        float u1 = tv0 ? (float)(base + 1) : -1.0f;
        float u2 = tv0 ? (float)(base + 2) : -1.0f;
        float u3 = tv1 ? (float)(base)     : -1.0f;
        float u4 = tv1 ? (float)(base + 2) : -1.0f;
        float u5 = tv1 ? (float)(base + 3) : -1.0f;
        v2f s0 = {u0, u1}, s1 = {u2, u3}, s2 = {u4, u5};
        v2f* uo = (v2f*)(uvidx_out + o);
        uo[0] = s0; uo[1] = s1; uo[2] = s2;
    } else {
        // ---------- UV atlas: one float4 (two corners) per thread ----------
        int k = (b - vBlocks - tBlocks) * blockDim.x + threadIdx.x;
        int npairs = Ngrid * Ngrid * 2;
        if (k >= npairs) return;
        int q = k >> 1;
        int h = k & 1;
        int gx = q % Ngrid;
        int gy = q / Ngrid;
        float x = (float)gx * step;
        float y = (float)gy * step;
        v4f out;
        if (h == 0) { out.x = x;       out.y = y;       out.z = x + pad; out.w = y; }
        else        { out.x = x + pad; out.y = y + pad; out.z = x;       out.w = y + pad; }
        uvs[k] = out;
    }
}

extern "C" void kernel_launch(void* const* d_in, const int* in_sizes, int n_in,
                              void* d_out, int out_size, void* d_ws, size_t ws_size,
                              hipStream_t stream) {
    const float* pos     = (const float*)d_in[0];
    const float* sdf     = (const float*)d_in[1];
    const int*   tet     = (const int*)d_in[2];
    const int*   edges   = (const int*)d_in[3];
    const int*   idx_map = (const int*)d_in[4];

    int Nv = in_sizes[0] / 3;
    int T  = in_sizes[2] / 4;
    int Eu = in_sizes[3] / 2;

    long long half = (2LL * T + 1) / 2;
    int Ngrid = (int)ceil(sqrt((double)half));
    while ((long long)Ngrid * Ngrid < half) Ngrid++;
    while ((long long)(Ngrid - 1) * (Ngrid - 1) >= half) Ngrid--;

    float* out   = (float*)d_out;
    float* verts = out;
    float* faces = verts + 3LL * Eu;
    float* uvs   = faces + 6LL * T;
    float* uvidx = uvs   + 8LL * Ngrid * Ngrid;

    float step = (float)((1.0 - 1.0 / (double)Ngrid) / (double)(Ngrid - 1));
    float pad  = 0.9f / (float)Ngrid;

    const int BLK = 256;
    bool usePacked = (ws_size >= (size_t)Nv * 8);
    v4h* packed = usePacked ? (v4h*)d_ws : nullptr;

    if (usePacked) {
        int pthreads = (Nv + 3) / 4;
        pack_kernel<<<(pthreads + BLK - 1) / BLK, BLK, 0, stream>>>(
            pos, sdf, packed, Nv);
    }

    int vthreads = (Eu + 3) / 4;
    int vBlocks = (vthreads + BLK - 1) / BLK;
    int tBlocks = (T + BLK - 1) / BLK;
    int npairs  = Ngrid * Ngrid * 2;
    int uBlocks = (npairs + BLK - 1) / BLK;

    dmtet_fused_kernel<<<vBlocks + tBlocks + uBlocks, BLK, 0, stream>>>(
        pos, sdf, tet, edges, idx_map, packed,
        verts, faces, uvidx, (v4f*)uvs,
        Eu, T, Ngrid, vBlocks, tBlocks, step, pad);
}